// Round 1
// baseline (2921.053 us; speedup 1.0000x reference)
//
#include <hip/hip_runtime.h>
#include <hip/hip_bf16.h>

#define B_DIM 512
#define H_DIM 512
#define BH (B_DIM * H_DIM)

typedef __attribute__((ext_vector_type(4))) float f32x4;
typedef __attribute__((ext_vector_type(8))) short s16x8;
typedef __attribute__((ext_vector_type(8))) unsigned short u16x8;
typedef __attribute__((ext_vector_type(4))) unsigned short u16x4;

// LDS: staging tiles (bf16, XOR-swizzled) unioned with the fp32 gate-exchange buffer.
union LdsU {
    struct {
        unsigned short A[64 * 64];    // [row=batch][k], swizzled   (8 KB)
        unsigned short Bt[128 * 64];  // [row=4*gate-cols][k], swz  (16 KB)
    } st;
    float gates[4][64][33];           // [gate][row][col] padded    (33 KB)
};

__device__ __forceinline__ unsigned short f2bf(float f) {
    unsigned int u = __builtin_bit_cast(unsigned int, f);
    u += 0x7FFFu + ((u >> 16) & 1u);   // round-to-nearest-even
    return (unsigned short)(u >> 16);
}

// G4: row-major [64-k] bf16 tile has 128B row stride -> 16/32-way bank conflict.
// byte ^= ((row&7)<<4) spreads 8 rows across 8 distinct 16B slots; preserves
// 8B/16B alignment (xor is a multiple of 16) and stays within the 128B row.
__device__ __forceinline__ void lds_store4(unsigned short* base, int row, int k0, u16x4 v) {
    int off = (((row << 6) + k0) << 1) ^ ((row & 7) << 4);
    *(u16x4*)((char*)base + off) = v;
}
__device__ __forceinline__ u16x8 lds_load8(const unsigned short* base, int row, int k0) {
    int off = (((row << 6) + k0) << 1) ^ ((row & 7) << 4);
    return *(const u16x8*)((const char*)base + off);
}

__device__ __forceinline__ float sigf(float x) { return 1.f / (1.f + __expf(-x)); }

// One LSTM cell for one (t, l): gates = in0 @ Wih^T + hprev @ Whh^T + bih + bhh,
// then c' = sig(f)*c + sig(i)*tanh(g); h' = sig(o)*tanh(c').
// Block: 256 threads = 4 waves; wave w computes gate w's 64x32 tile.
// Grid: (B/64, H/32) = (8, 16).
__global__ __launch_bounds__(256)
void lstm_cell(const float* __restrict__ in0, const float* __restrict__ hprev,
               const float* __restrict__ Wih, const float* __restrict__ Whh,
               const float* __restrict__ bih, const float* __restrict__ bhh,
               float* __restrict__ cbuf, float* __restrict__ hout,
               float* __restrict__ yout, float* __restrict__ hN, float* __restrict__ cN,
               int first)
{
    __shared__ LdsU lds;
    const int tid  = threadIdx.x;
    const int lane = tid & 63;
    const int w    = tid >> 6;          // wave id == gate id (i,f,g,o)
    const int b0   = blockIdx.x * 64;   // batch-row base
    const int j0   = blockIdx.y * 32;   // per-gate hidden-col base

    f32x4 acc[4][2] = {};               // 4 row-frags x 2 col-frags of 16x16

    const int nchunks = first ? 8 : 16; // t==0: h,c are zero -> skip hprev half

    // staging assignment (per K-chunk of 64):
    const int ar  = tid >> 2;           // A row 0..63
    const int ak  = (tid & 3) << 4;     // A k0 in {0,16,32,48}, 16 floats each
    const int br  = tid >> 1;           // B row 0..127 (gate*32 + col-in-gate)
    const int bk  = (tid & 1) << 5;     // B k0 in {0,32}, 32 floats each
    const int bg  = br >> 5;
    const int brr = br & 31;

    for (int c = 0; c < nchunks; ++c) {
        const float* Asrc = (c < 8) ? in0 : hprev;
        const float* Wsrc = (c < 8) ? Wih : Whh;
        const int kg = (c & 7) << 6;

        // ---- stage A: 64x64 fp32 -> bf16 LDS ----
        const float* ap = Asrc + (size_t)(b0 + ar) * H_DIM + kg + ak;
        #pragma unroll
        for (int q = 0; q < 4; ++q) {
            f32x4 v = *(const f32x4*)(ap + 4 * q);
            u16x4 p;
            p[0] = f2bf(v[0]); p[1] = f2bf(v[1]); p[2] = f2bf(v[2]); p[3] = f2bf(v[3]);
            lds_store4(lds.st.A, ar, ak + 4 * q, p);
        }
        // ---- stage B: 128x64 fp32 weights -> bf16 LDS (rows = W[g*512+j0+rr]) ----
        const float* bp = Wsrc + (size_t)(bg * 512 + j0 + brr) * H_DIM + kg + bk;
        #pragma unroll
        for (int q = 0; q < 8; ++q) {
            f32x4 v = *(const f32x4*)(bp + 4 * q);
            u16x4 p;
            p[0] = f2bf(v[0]); p[1] = f2bf(v[1]); p[2] = f2bf(v[2]); p[3] = f2bf(v[3]);
            lds_store4(lds.st.Bt, br, bk + 4 * q, p);
        }
        __syncthreads();

        // ---- MFMA: 2 k-steps of 32 ----
        #pragma unroll
        for (int kk = 0; kk < 64; kk += 32) {
            const int krd = kk + ((lane >> 4) << 3);
            u16x8 a[4], b[2];
            #pragma unroll
            for (int fr = 0; fr < 4; ++fr)
                a[fr] = lds_load8(lds.st.A, fr * 16 + (lane & 15), krd);
            #pragma unroll
            for (int fc = 0; fc < 2; ++fc)
                b[fc] = lds_load8(lds.st.Bt, w * 32 + fc * 16 + (lane & 15), krd);
            #pragma unroll
            for (int fr = 0; fr < 4; ++fr)
                #pragma unroll
                for (int fc = 0; fc < 2; ++fc)
                    acc[fr][fc] = __builtin_amdgcn_mfma_f32_16x16x32_bf16(
                        __builtin_bit_cast(s16x8, a[fr]),
                        __builtin_bit_cast(s16x8, b[fc]),
                        acc[fr][fc], 0, 0, 0);
        }
        __syncthreads();
    }

    // ---- epilogue: gates (+bias) to LDS for cross-wave exchange ----
    // C/D layout (m89): col = lane&15, row = (lane>>4)*4 + reg.
    #pragma unroll
    for (int fc = 0; fc < 2; ++fc) {
        const int jl = fc * 16 + (lane & 15);
        const int n  = w * 512 + j0 + jl;
        const float bias = bih[n] + bhh[n];
        #pragma unroll
        for (int fr = 0; fr < 4; ++fr)
            #pragma unroll
            for (int r = 0; r < 4; ++r)
                lds.gates[w][fr * 16 + ((lane >> 4) << 2) + r][jl] = acc[fr][fc][r] + bias;
    }
    __syncthreads();

    // ---- elementwise LSTM update: each thread owns 8 (row, col) cells ----
    const int row = tid >> 2;
    const int c0  = (tid & 3) << 3;
    #pragma unroll
    for (int jj = 0; jj < 8; ++jj) {
        const int col = c0 + jj;
        const float gi = lds.gates[0][row][col];
        const float gf = lds.gates[1][row][col];
        const float gg = lds.gates[2][row][col];
        const float go = lds.gates[3][row][col];
        const int idx = (b0 + row) * H_DIM + j0 + col;
        const float cp = first ? 0.f : cbuf[idx];
        const float cv = sigf(gf) * cp + sigf(gi) * tanhf(gg);
        const float hv = sigf(go) * tanhf(cv);
        cbuf[idx] = cv;
        hout[idx] = hv;
        if (yout) yout[idx] = hv;
        if (hN)   hN[idx]   = hv;
        if (cN)   cN[idx]   = cv;
    }
}

extern "C" void kernel_launch(void* const* d_in, const int* in_sizes, int n_in,
                              void* d_out, int out_size, void* d_ws, size_t ws_size,
                              hipStream_t stream) {
    const float* x   = (const float*)d_in[0];  // [30][512][512]
    const float* Wih = (const float*)d_in[1];  // [30][2][2048][512]
    const float* Whh = (const float*)d_in[2];  // [30][2][2048][512]
    const float* bih = (const float*)d_in[3];  // [30][2][2048]
    const float* bhh = (const float*)d_in[4];  // [30][2][2048]

    float* out = (float*)d_out;
    float* ys  = out;               // [30][512][512]
    float* hNo = out + 30 * (size_t)BH;  // [2][512][512]
    float* cNo = out + 32 * (size_t)BH;  // [2][512][512]

    // workspace: h ping-pong [layer][parity][BH] + c [layer][BH] = 6.3 MB
    float* hbuf = (float*)d_ws;
    float* cbuf = hbuf + 4 * (size_t)BH;

    for (int t = 0; t < 30; ++t) {
        const int te = (t < 29) ? t : 28;   // faithful source bug: step 29 reuses x[28]
        for (int l = 0; l < 2; ++l) {
            const float* in0 = (l == 0) ? (x + (size_t)te * BH)
                                        : (hbuf + (size_t)(t & 1) * BH); // layer0 h, this step
            const float* hp  = hbuf + (size_t)(l * 2 + ((t + 1) & 1)) * BH; // own h, prev step
            const size_t wo = (size_t)(t * 2 + l) * 2048 * 512;
            const size_t bo = (size_t)(t * 2 + l) * 2048;
            lstm_cell<<<dim3(8, 16), 256, 0, stream>>>(
                in0, hp, Wih + wo, Whh + wo, bih + bo, bhh + bo,
                cbuf + (size_t)l * BH,
                hbuf + (size_t)(l * 2 + (t & 1)) * BH,
                (l == 1) ? (ys + (size_t)t * BH) : nullptr,
                (t == 29) ? (hNo + (size_t)l * BH) : nullptr,
                (t == 29) ? (cNo + (size_t)l * BH) : nullptr,
                (t == 0) ? 1 : 0);
        }
    }
}

// Round 2
// 1421.899 us; speedup vs baseline: 2.0543x; 2.0543x over previous
//
#include <hip/hip_runtime.h>

typedef __attribute__((ext_vector_type(4))) float f32x4;
typedef __attribute__((ext_vector_type(8))) short s16x8;
typedef __attribute__((ext_vector_type(8))) unsigned short u16x8;

#define BH (512 * 512)
#define NKB 16            // K=512 -> 16 k-blocks of 32
#define PW_MAT 1048576LL  // elems per packed weight matrix [c16=128][kb=16][lane=64][e=8]
#define PX_STEP 262144LL  // elems per packed activation   [r16=32][kb=16][lane=64][e=8]

// Packed fragment layout (m97 both-row-major MFMA operands, verified in round 1):
// frag(rb, kb): lane l holds M[rb*16 + (l&15)][kb*32 + (l>>4)*8 + e], e=0..7.
// Stored so one wave's frag = 64 lanes x 16B contiguous -> single coalesced
// global_load_dwordx4 per lane, straight into MFMA operand registers. No LDS.

__device__ __forceinline__ unsigned short f2bf(float f) {
    unsigned int u = __builtin_bit_cast(unsigned int, f);
    u += 0x7FFFu + ((u >> 16) & 1u);   // RNE
    return (unsigned short)(u >> 16);
}
__device__ __forceinline__ float sigf(float x) { return 1.f / (1.f + __expf(-x)); }

// ---------- pack weights fp32 -> bf16 fragment order ----------
// One thread per 8-elem oct. Reads 32B coalesced; writes 16B semi-scattered.
__global__ __launch_bounds__(256) void pack_w_kernel(
    const float* __restrict__ Wih, const float* __restrict__ Whh,
    unsigned short* __restrict__ PW)
{
    const long long OCTS = 30LL * 2 * 2048 * 64;   // 7,864,320 per matrix-set
    long long tid = (long long)blockIdx.x * 256 + threadIdx.x;
    if (tid >= 2 * OCTS) return;
    int mat = tid >= OCTS;
    long long r = mat ? tid - OCTS : tid;          // oct index, row-major over [30][2][2048][512/8]
    const float* src = (mat ? Whh : Wih) + r * 8;
    f32x4 v0 = *(const f32x4*)src;
    f32x4 v1 = *(const f32x4*)(src + 4);
    u16x8 p;
    p[0]=f2bf(v0[0]); p[1]=f2bf(v0[1]); p[2]=f2bf(v0[2]); p[3]=f2bf(v0[3]);
    p[4]=f2bf(v1[0]); p[5]=f2bf(v1[1]); p[6]=f2bf(v1[2]); p[7]=f2bf(v1[3]);
    int oct = (int)(r & 63);
    long long rowg = r >> 6;
    int row = (int)(rowg & 2047);
    long long tl = rowg >> 11;                     // t*2+l
    int c16 = row >> 4, lanelo = row & 15, kb = oct >> 2, hi = oct & 3;
    int lane = lanelo | (hi << 4);
    long long dst = (tl * 2 + mat) * PW_MAT + (long long)((c16 * NKB + kb) * 64 + lane) * 8;
    *(u16x8*)(PW + dst) = p;
}

// ---------- pack x fp32 -> bf16 fragment order (steps 0..28; step 29 reuses 28) ----
__global__ __launch_bounds__(256) void pack_x_kernel(
    const float* __restrict__ x, unsigned short* __restrict__ PX)
{
    long long tid = (long long)blockIdx.x * 256 + threadIdx.x;
    if (tid >= 29LL * 32768) return;
    int t = (int)(tid >> 15);
    int r = (int)(tid & 32767);
    int row = r >> 6, oct = r & 63;
    const float* src = x + ((long long)t * 512 + row) * 512 + oct * 8;
    f32x4 v0 = *(const f32x4*)src;
    f32x4 v1 = *(const f32x4*)(src + 4);
    u16x8 p;
    p[0]=f2bf(v0[0]); p[1]=f2bf(v0[1]); p[2]=f2bf(v0[2]); p[3]=f2bf(v0[3]);
    p[4]=f2bf(v1[0]); p[5]=f2bf(v1[1]); p[6]=f2bf(v1[2]); p[7]=f2bf(v1[3]);
    int c16 = row >> 4, lanelo = row & 15, kb = oct >> 2, hi = oct & 3;
    int lane = lanelo | (hi << 4);
    *(u16x8*)(PX + (long long)t * PX_STEP + (long long)((c16 * NKB + kb) * 64 + lane) * 8) = p;
}

// ---------- bsum = bih + bhh ----------
__global__ __launch_bounds__(256) void bsum_kernel(
    const float* __restrict__ bih, const float* __restrict__ bhh, float* __restrict__ bs)
{
    int i = blockIdx.x * 256 + threadIdx.x;
    if (i < 30 * 2 * 2048) bs[i] = bih[i] + bhh[i];
}

// ---------- G0[t] = x[te] @ Wih[t,0]^T + bsum[t,0]  (all steps, parallel) ----------
// grid (8 rowblk, 32 colgrp, 30 t), 4 waves; wave w: 64 rows x 16 cols, acc[4].
__global__ __launch_bounds__(256) void g0_kernel(
    const unsigned short* __restrict__ PX, const unsigned short* __restrict__ PW,
    const float* __restrict__ bs, float* __restrict__ G0)
{
    int lane = threadIdx.x & 63, w = threadIdx.x >> 6;
    int bx = blockIdx.x, by = blockIdx.y, t = blockIdx.z;
    int te = t < 29 ? t : 28;   // source bug: step 29 reuses x[28] (weights still t=29)
    const u16x8* A = (const u16x8*)(PX + (long long)te * PX_STEP);
    const u16x8* B = (const u16x8*)(PW + (long long)(t * 2 + 0) * 2 * PW_MAT); // (t, l=0, ih)
    int c16 = by * 4 + w;
    f32x4 acc[4] = {};
    #pragma unroll
    for (int kb = 0; kb < 16; ++kb) {
        u16x8 b = B[(c16 * NKB + kb) * 64 + lane];
        #pragma unroll
        for (int fr = 0; fr < 4; ++fr) {
            u16x8 a = A[((bx * 4 + fr) * NKB + kb) * 64 + lane];
            acc[fr] = __builtin_amdgcn_mfma_f32_16x16x32_bf16(
                __builtin_bit_cast(s16x8, a), __builtin_bit_cast(s16x8, b), acc[fr], 0, 0, 0);
        }
    }
    int col = c16 * 16 + (lane & 15);
    float bias = bs[(t * 2 + 0) * 2048 + col];
    float* Gt = G0 + (long long)t * 512 * 2048;
    #pragma unroll
    for (int fr = 0; fr < 4; ++fr)
        #pragma unroll
        for (int r = 0; r < 4; ++r) {
            int row = bx * 64 + fr * 16 + ((lane >> 4) << 2) + r;
            Gt[row * 2048 + col] = acc[fr][r] + bias;
        }
}

// ---------- LSTM cell ----------
// grid (32 rowblk of 16, 16 colblk of 32), 512 thr = 8 waves.
// wave w: gate = w&3, kh = w>>2 (K-half / loop split). acc[1][2]: 16 rows x 32 cols.
// L1 (PAin!=null): kh0 -> input-proj loop (16 kb), kh1 -> recurrent loop (16 kb).
// L0 (PAin==null): recurrent loop split kb 0-7 / 8-15 across kh.
// first step: PArec==null -> recurrent skipped, c_prev = 0.
__global__ __launch_bounds__(512) void cell_kernel(
    const unsigned short* __restrict__ PAin,  const unsigned short* __restrict__ PBin,
    const unsigned short* __restrict__ PArec, const unsigned short* __restrict__ PBrec,
    const float* __restrict__ G0t, const float* __restrict__ bs,
    float* __restrict__ cbuf, unsigned short* __restrict__ hpk,
    float* __restrict__ yout, float* __restrict__ hNo, float* __restrict__ cNo)
{
    __shared__ float g[8][16][33];
    const int tid = threadIdx.x, lane = tid & 63, w = tid >> 6;
    const int gate = w & 3, kh = w >> 2;
    const int bx = blockIdx.x, by = blockIdx.y;
    const int c0 = gate * 32 + by * 2;    // B c16 base for this gate/col-block
    f32x4 acc0 = {}, acc1 = {};

    if (PAin) {   // layer 1
        const u16x8* A = nullptr; const u16x8* B = nullptr;
        if (kh == 0)      { A = (const u16x8*)PAin;  B = (const u16x8*)PBin;  }
        else if (PArec)   { A = (const u16x8*)PArec; B = (const u16x8*)PBrec; }
        if (A) {
            #pragma unroll
            for (int kb = 0; kb < 16; ++kb) {
                u16x8 av = A[(bx * NKB + kb) * 64 + lane];
                u16x8 b0 = B[(c0 * NKB + kb) * 64 + lane];
                u16x8 b1 = B[((c0 + 1) * NKB + kb) * 64 + lane];
                acc0 = __builtin_amdgcn_mfma_f32_16x16x32_bf16(
                    __builtin_bit_cast(s16x8, av), __builtin_bit_cast(s16x8, b0), acc0, 0, 0, 0);
                acc1 = __builtin_amdgcn_mfma_f32_16x16x32_bf16(
                    __builtin_bit_cast(s16x8, av), __builtin_bit_cast(s16x8, b1), acc1, 0, 0, 0);
            }
        }
    } else if (PArec) {   // layer 0, recurrent only, K split across kh
        const u16x8* A = (const u16x8*)PArec; const u16x8* B = (const u16x8*)PBrec;
        #pragma unroll
        for (int i = 0; i < 8; ++i) {
            int kb = kh * 8 + i;
            u16x8 av = A[(bx * NKB + kb) * 64 + lane];
            u16x8 b0 = B[(c0 * NKB + kb) * 64 + lane];
            u16x8 b1 = B[((c0 + 1) * NKB + kb) * 64 + lane];
            acc0 = __builtin_amdgcn_mfma_f32_16x16x32_bf16(
                __builtin_bit_cast(s16x8, av), __builtin_bit_cast(s16x8, b0), acc0, 0, 0, 0);
            acc1 = __builtin_amdgcn_mfma_f32_16x16x32_bf16(
                __builtin_bit_cast(s16x8, av), __builtin_bit_cast(s16x8, b1), acc1, 0, 0, 0);
        }
    }

    // C/D layout: col = lane&15, row = (lane>>4)*4 + reg (m89)
    #pragma unroll
    for (int r = 0; r < 4; ++r) {
        g[w][((lane >> 4) << 2) + r][(lane & 15)]      = acc0[r];
        g[w][((lane >> 4) << 2) + r][16 + (lane & 15)] = acc1[r];
    }
    __syncthreads();

    // elementwise: 512 threads, one cell each
    const int rl = tid >> 5, cl = tid & 31;
    const int rowg = bx * 16 + rl, colH = by * 32 + cl;
    float gv[4];
    #pragma unroll
    for (int q = 0; q < 4; ++q) {
        float v = g[q][rl][cl] + g[q + 4][rl][cl];
        int n = q * 512 + colH;
        v += G0t ? G0t[rowg * 2048 + n] : bs[n];
        gv[q] = v;
    }
    const int idx = rowg * 512 + colH;
    float cp = PArec ? cbuf[idx] : 0.f;
    float cv = sigf(gv[1]) * cp + sigf(gv[0]) * tanhf(gv[2]);
    float hv = sigf(gv[3]) * tanhf(cv);
    cbuf[idx] = cv;
    // packed h (A-operand layout for next GEMMs): r16=bx, kb=by, lane=(rl)|(hi<<4)
    int lp = rl | (((cl >> 3) & 3) << 4);
    hpk[(long long)((bx * NKB + by) * 64 + lp) * 8 + (cl & 7)] = f2bf(hv);
    if (yout) yout[idx] = hv;
    if (hNo)  hNo[idx]  = hv;
    if (cNo)  cNo[idx]  = cv;
}

extern "C" void kernel_launch(void* const* d_in, const int* in_sizes, int n_in,
                              void* d_out, int out_size, void* d_ws, size_t ws_size,
                              hipStream_t stream) {
    const float* x   = (const float*)d_in[0];
    const float* Wih = (const float*)d_in[1];
    const float* Whh = (const float*)d_in[2];
    const float* bih = (const float*)d_in[3];
    const float* bhh = (const float*)d_in[4];

    float* out = (float*)d_out;
    float* ys  = out;                    // [30][512][512]
    float* hNo = out + 30LL * BH;        // [2][512][512]
    float* cNo = out + 32LL * BH;

    // workspace layout (~398 MB)
    unsigned short* PW = (unsigned short*)d_ws;              // 60*2*1M bf16 = 252 MB
    unsigned short* PX = PW + 60LL * 2 * PW_MAT;             // 30 * 512 KB
    float* G0   = (float*)(PX + 30LL * PX_STEP);             // 30 * 4 MB fp32
    float* bsum = G0 + 30LL * 512 * 2048;                    // 480 KB
    float* C    = bsum + 30 * 2 * 2048;                      // c0,c1 fp32, 2 MB
    unsigned short* H = (unsigned short*)(C + 2LL * BH);     // h0[2],h1[2] packed bf16, 2 MB

    pack_w_kernel<<<61440, 256, 0, stream>>>(Wih, Whh, PW);
    pack_x_kernel<<<3712, 256, 0, stream>>>(x, PX);
    bsum_kernel<<<480, 256, 0, stream>>>(bih, bhh, bsum);
    g0_kernel<<<dim3(8, 32, 30), 256, 0, stream>>>(PX, PW, bsum, G0);

    for (int t = 0; t < 30; ++t) {
        const int cur = t & 1, prv = cur ^ 1;
        unsigned short* h0c = H + (long long)cur * PX_STEP;
        unsigned short* h0p = H + (long long)prv * PX_STEP;
        unsigned short* h1c = H + (long long)(2 + cur) * PX_STEP;
        unsigned short* h1p = H + (long long)(2 + prv) * PX_STEP;
        // layer 0: gates = G0[t] + h0_prev @ Whh[t,0]^T  (bias already in G0)
        cell_kernel<<<dim3(32, 16), 512, 0, stream>>>(
            nullptr, nullptr,
            t ? h0p : nullptr, PW + ((long long)(t * 2 + 0) * 2 + 1) * PW_MAT,
            G0 + (long long)t * 512 * 2048, nullptr,
            C, h0c,
            nullptr, (t == 29) ? hNo : nullptr, (t == 29) ? cNo : nullptr);
        // layer 1: gates = h0_cur @ Wih[t,1]^T + h1_prev @ Whh[t,1]^T + bsum[t,1]
        cell_kernel<<<dim3(32, 16), 512, 0, stream>>>(
            h0c, PW + ((long long)(t * 2 + 1) * 2 + 0) * PW_MAT,
            t ? h1p : nullptr, PW + ((long long)(t * 2 + 1) * 2 + 1) * PW_MAT,
            nullptr, bsum + (t * 2 + 1) * 2048,
            C + BH, h1c,
            ys + (long long)t * BH, (t == 29) ? hNo + BH : nullptr, (t == 29) ? cNo + BH : nullptr);
    }
}